// Round 5
// baseline (894.000 us; speedup 1.0000x reference)
//
#include <hip/hip_runtime.h>
#include <hip/hip_bf16.h>

#define NN 10000
#define NE 50000
#define FIN 40
#define FE 10
// L = 64

typedef float f32x4 __attribute__((ext_vector_type(4)));
typedef short s16x8 __attribute__((ext_vector_type(8)));

__device__ __forceinline__ float bcast(float v, int lane) {
    return __uint_as_float(__builtin_amdgcn_readlane(__float_as_uint(v), lane));
}
__device__ __forceinline__ ushort f2bf(float f) {
    uint u = __float_as_uint(f);
    uint r = (u + 0x7FFFu + ((u >> 16) & 1u)) >> 16;
    return (ushort)r;
}
__device__ __forceinline__ float bf2f(ushort h) {
    return __uint_as_float(((uint)h) << 16);
}

// ---------------- CSR build ----------------
__global__ void k_count(const int* __restrict__ ei, int* __restrict__ deg) {
    int e = blockIdx.x * 256 + threadIdx.x;
    if (e < NE) atomicAdd(&deg[ei[NE + e]], 1);
}

__global__ __launch_bounds__(1024) void k_scan(const int* __restrict__ deg,
                                               int* __restrict__ rowp,
                                               int* __restrict__ fill,
                                               float* __restrict__ invd) {
    __shared__ int wsum[16];
    __shared__ int chunkbase;
    int tid = threadIdx.x, lane = tid & 63, wv = tid >> 6;
    if (tid == 0) chunkbase = 0;
    __syncthreads();
    for (int base = 0; base < NN; base += 1024) {
        int idx = base + tid;
        int v = (idx < NN) ? deg[idx] : 0;
        int s = v;
#pragma unroll
        for (int off = 1; off < 64; off <<= 1) {
            int t = __shfl_up(s, off, 64);
            if (lane >= off) s += t;
        }
        if (lane == 63) wsum[wv] = s;
        __syncthreads();
        int carry = chunkbase;
        if (wv == 0 && lane < 16) {
            int x = wsum[lane];
#pragma unroll
            for (int off = 1; off < 16; off <<= 1) {
                int t = __shfl_up(x, off, 64);
                if (lane >= off) x += t;
            }
            wsum[lane] = x;  // inclusive over waves
        }
        __syncthreads();
        int wpre = (wv == 0) ? 0 : wsum[wv - 1];
        int incl = carry + wpre + s;
        if (idx < NN) {
            rowp[idx] = incl - v;
            fill[idx] = incl - v;
            invd[idx] = 1.0f / (float)(v > 0 ? v : 1);
        }
        __syncthreads();
        if (tid == 0) chunkbase = carry + wsum[15];
        __syncthreads();
    }
    if (tid == 0) rowp[NN] = NE;
}

__global__ void k_fill(const int* __restrict__ ei, int* __restrict__ fill,
                       int* __restrict__ csrs, int* __restrict__ csre) {
    int e = blockIdx.x * 256 + threadIdx.x;
    if (e < NE) {
        int d = ei[NE + e];
        int p = atomicAdd(&fill[d], 1);
        csrs[p] = ei[e];
        csre[p] = e;
    }
}

// ---------------- W2 split-bf16, transposed to [o][ki] (ki = k*64+i) ----------------
__global__ __launch_bounds__(256) void k_w2f(const float* __restrict__ n2w,
                                             ushort* __restrict__ W2FH,
                                             ushort* __restrict__ W2FL) {
    int lane = threadIdx.x & 63, wvl = threadIdx.x >> 6;
    int ki = blockIdx.x * 4 + wvl;
    float v = n2w[(size_t)ki * 64 + lane];
    ushort hi = f2bf(v);
    ushort lo = f2bf(v - bf2f(hi));
    W2FH[(size_t)lane * 4096 + ki] = hi;
    W2FL[(size_t)lane * 4096 + ki] = lo;
}

// ---------------- edge MLP: hE = relu(edge_attr @ nn1_w + nn1_b) ----------------
__global__ __launch_bounds__(256) void k_edge_h(const float* __restrict__ ea,
                                                const float* __restrict__ w1,
                                                const float* __restrict__ b1,
                                                float* __restrict__ hE) {
    int lane = threadIdx.x & 63, wv = threadIdx.x >> 6;
    int e = blockIdx.x * 4 + wv;
    float av = (lane < FE) ? ea[e * FE + lane] : 0.f;
    float acc = b1[lane];
#pragma unroll
    for (int j = 0; j < FE; ++j) acc += bcast(av, j) * w1[j * 64 + lane];
    hE[e * 64 + lane] = fmaxf(acc, 0.f);
}

// ---------------- lin0 ----------------
__global__ __launch_bounds__(256) void k_lin0(const float* __restrict__ x,
                                              const float* __restrict__ w0,
                                              const float* __restrict__ b0,
                                              float* __restrict__ F) {
    int lane = threadIdx.x & 63, wv = threadIdx.x >> 6;
    int n = blockIdx.x * 4 + wv;
    float xv = (lane < FIN) ? x[n * FIN + lane] : 0.f;
    float acc = b0[lane];
#pragma unroll
    for (int k = 0; k < FIN; ++k) acc += bcast(xv, k) * w0[k * 64 + lane];
    F[n * 64 + lane] = fmaxf(acc, 0.f);
}

// ---------------- fused NNConv + GRU via MFMA (split bf16) ----------------
// 1024 thr = 16 waves = 8 nodes; node = wv>>1, khalf = wv&1 so the G
// accumulator is only 32 VGPRs/thread (anti-spill: compiler pinned us at
// 64 VGPRs in R2/R3 and spilled G[64] -> 35 MB scratch traffic).
// Phase A: each wave of the pair accumulates its k-half of G over the edges.
// 4 k-chunks: owning wave converts ->LDS bf16 hi/lo, all 16 waves MFMA
// (otile=wv&3, kq=wv>>2); A rows 8..15 zero. Reduce kq via LDS. Epilogue
// (root, nn2_b, GRU) also pair-split over k with LDS combine.
__global__ __launch_bounds__(1024) void k_mp(
    const float* __restrict__ F, const float* __restrict__ hE,
    const int* __restrict__ rowp, const int* __restrict__ csrs,
    const int* __restrict__ csre,
    const ushort* __restrict__ W2FH, const ushort* __restrict__ W2FL,
    const float* __restrict__ B2, const float* __restrict__ invd,
    const float* __restrict__ Wroot, const float* __restrict__ broot,
    const float* __restrict__ Wih, const float* __restrict__ Whh,
    const float* __restrict__ bih, const float* __restrict__ bhh,
    float* __restrict__ Fout) {
    __shared__ __align__(16) char smem[59648];
    ushort(*GH)[1032] = (ushort(*)[1032])smem;              // [8][1032] 16512 B
    ushort(*GL)[1032] = (ushort(*)[1032])(smem + 16512);    // 16512 B
    float(*Us)[64] = (float(*)[64])(smem + 33024);          // [8][64] 2048 B
    float(*Pb)[64] = (float(*)[64])(smem + 35072);          // [16][64] 4096 B
    float(*Pr)[64] = (float(*)[64])(smem + 39168);          // [16][64] 4096 B
    float(*Pg)[256] = (float(*)[256])(smem + 43264);        // [16][256] 16384 B
    float(*Red)[256] = (float(*)[256])smem;                 // union over GH
    float(*Agg)[64] = (float(*)[64])(smem + 16512);         // union over GL

    int tid = threadIdx.x, lane = tid & 63, wv = tid >> 6;
    int node = wv >> 1, kh = wv & 1;
    int n = __builtin_amdgcn_readfirstlane(blockIdx.x * 8 + node);

    // ---- phase A: G[kk] = sum_e hE[e][kh*32+kk] * F[src][lane], kk<32 ----
    float G[32];
#pragma unroll
    for (int k = 0; k < 32; ++k) G[k] = 0.f;
    float usum = 0.f;
    int beg = rowp[n], end = rowp[n + 1];
    for (int p = beg; p < end; ++p) {
        int s = __builtin_amdgcn_readfirstlane(csrs[p]);
        int e = __builtin_amdgcn_readfirstlane(csre[p]);
        float u = F[(size_t)s * 64 + lane];
        const float* hp = hE + (size_t)e * 64 + kh * 32;  // uniform -> s_load
        usum += u;
#pragma unroll
        for (int kk = 0; kk < 32; ++kk) G[kk] = fmaf(hp[kk], u, G[kk]);
    }
    if (kh == 0) Us[node][lane] = usum;

    // ---- MFMA phase: 4 chunks of 16 k's; chunk c owned by wave kh==(c>>1) ----
    f32x4 acc = {0.f, 0.f, 0.f, 0.f};
    int otile = wv & 3, kq = wv >> 2;
    int arow = lane & 15, agrp = lane >> 4;
    int o = otile * 16 + arow;
    const ushort* bhbase = W2FH + (size_t)o * 4096;
    const ushort* blbase = W2FL + (size_t)o * 4096;
#pragma unroll
    for (int c = 0; c < 4; ++c) {
        if ((c >> 1) == kh) {
#pragma unroll
            for (int kk = 0; kk < 16; ++kk) {
                float g = G[(c & 1) * 16 + kk];
                ushort hi = f2bf(g);
                ushort lo = f2bf(g - bf2f(hi));
                GH[node][kk * 64 + lane] = hi;
                GL[node][kk * 64 + lane] = lo;
            }
        }
        __syncthreads();
#pragma unroll
        for (int s8 = 0; s8 < 8; ++s8) {
            int ki = (kq * 8 + s8) * 32 + agrp * 8;
            s16x8 ah = {0, 0, 0, 0, 0, 0, 0, 0};
            s16x8 al = {0, 0, 0, 0, 0, 0, 0, 0};
            if (arow < 8) {
                ah = *(const s16x8*)&GH[arow][ki];
                al = *(const s16x8*)&GL[arow][ki];
            }
            s16x8 bh = *(const s16x8*)&bhbase[c * 1024 + ki];
            s16x8 bl = *(const s16x8*)&blbase[c * 1024 + ki];
            acc = __builtin_amdgcn_mfma_f32_16x16x32_bf16(ah, bh, acc, 0, 0, 0);
            acc = __builtin_amdgcn_mfma_f32_16x16x32_bf16(ah, bl, acc, 0, 0, 0);
            acc = __builtin_amdgcn_mfma_f32_16x16x32_bf16(al, bh, acc, 0, 0, 0);
        }
        __syncthreads();
    }

    // ---- reduce partial D over the 4 kq groups ----
    *(f32x4*)&Red[wv][lane * 4] = acc;
    __syncthreads();
    if (wv < 4) {
        int t = wv;
        f32x4 s0 = *(f32x4*)&Red[t][lane * 4];
        f32x4 s1 = *(f32x4*)&Red[t + 4][lane * 4];
        f32x4 s2 = *(f32x4*)&Red[t + 8][lane * 4];
        f32x4 s3 = *(f32x4*)&Red[t + 12][lane * 4];
        f32x4 ss = s0 + s1 + s2 + s3;
        // D[row=node=(lane>>4)*4+r][col=o=t*16+(lane&15)]; rows>=8 unused
#pragma unroll
        for (int r = 0; r < 4; ++r) {
            int row = (lane >> 4) * 4 + r;
            if (row < 8) Agg[row][t * 16 + (lane & 15)] = ss[r];
        }
    }
    __syncthreads();

    // ---- epilogue, pair-split over k: b2t + root partials ----
    float b2t_p = 0.f;
#pragma unroll
    for (int i = 0; i < 32; ++i) {
        int ii = kh * 32 + i;
        b2t_p = fmaf(Us[node][ii], B2[ii * 64 + lane], b2t_p);
    }
    const float* frow = F + (size_t)n * 64 + kh * 32;  // uniform -> s_load
    float r_p = (kh == 0) ? broot[lane] : 0.f;
#pragma unroll
    for (int k = 0; k < 32; ++k)
        r_p = fmaf(frow[k], Wroot[(kh * 32 + k) * 64 + lane], r_p);
    Pb[wv][lane] = b2t_p;
    Pr[wv][lane] = r_p;
    __syncthreads();

    float b2t = Pb[node * 2][lane] + Pb[node * 2 + 1][lane];
    float rsum = Pr[node * 2][lane] + Pr[node * 2 + 1][lane];
    float a = (Agg[node][lane] + b2t) * invd[n];
    float m = fmaxf(a + rsum, 0.f);

    // ---- GRU partials over this wave's k-half ----
    float h = F[(size_t)n * 64 + lane];
    float sr = 0.f, sz = 0.f, gin = 0.f, ghn = 0.f;
#pragma unroll
    for (int k = 0; k < 32; ++k) {
        int kg = kh * 32 + k;
        float mk = bcast(m, kg), hk = bcast(h, kg);
        const float* wi = &Wih[kg * 192];
        const float* wh = &Whh[kg * 192];
        sr = fmaf(mk, wi[lane], fmaf(hk, wh[lane], sr));
        sz = fmaf(mk, wi[64 + lane], fmaf(hk, wh[64 + lane], sz));
        gin = fmaf(mk, wi[128 + lane], gin);
        ghn = fmaf(hk, wh[128 + lane], ghn);
    }
    Pg[wv][0 * 64 + lane] = sr;
    Pg[wv][1 * 64 + lane] = sz;
    Pg[wv][2 * 64 + lane] = gin;
    Pg[wv][3 * 64 + lane] = ghn;
    __syncthreads();

    if (kh == 0) {
        float srf = Pg[wv][0 * 64 + lane] + Pg[wv + 1][0 * 64 + lane] +
                    bih[lane] + bhh[lane];
        float szf = Pg[wv][1 * 64 + lane] + Pg[wv + 1][1 * 64 + lane] +
                    bih[64 + lane] + bhh[64 + lane];
        float ginf = Pg[wv][2 * 64 + lane] + Pg[wv + 1][2 * 64 + lane] +
                     bih[128 + lane];
        float ghnf = Pg[wv][3 * 64 + lane] + Pg[wv + 1][3 * 64 + lane] +
                     bhh[128 + lane];
        float rr = 1.f / (1.f + __expf(-srf));
        float zz = 1.f / (1.f + __expf(-szf));
        float ng = tanhf(ginf + rr * ghnf);
        Fout[(size_t)n * 64 + lane] = (1.f - zz) * ng + zz * h;
    }
}

// ---------------- final ----------------
__global__ __launch_bounds__(256) void k_final(const float* __restrict__ F,
                                               const float* __restrict__ W1,
                                               const float* __restrict__ b1f,
                                               const float* __restrict__ W2l,
                                               const float* __restrict__ b2f,
                                               float* __restrict__ out) {
    int lane = threadIdx.x & 63, wv = threadIdx.x >> 6;
    int n = blockIdx.x * 4 + wv;
    float fv = F[n * 64 + lane];
    float acc = b1f[lane];
#pragma unroll
    for (int k = 0; k < 64; ++k) acc += bcast(fv, k) * W1[k * 64 + lane];
    acc = fmaxf(acc, 0.f);
    float p = acc * W2l[lane];
#pragma unroll
    for (int off = 32; off; off >>= 1) p += __shfl_xor(p, off, 64);
    if (lane == 0) out[n] = p + b2f[0];
}

extern "C" void kernel_launch(void* const* d_in, const int* in_sizes, int n_in,
                              void* d_out, int out_size, void* d_ws, size_t ws_size,
                              hipStream_t stream) {
    const float* x = (const float*)d_in[0];
    const int* ei = (const int*)d_in[1];
    const float* ea = (const float*)d_in[2];
    const float* l0w = (const float*)d_in[3];
    const float* l0b = (const float*)d_in[4];
    const float* n1w = (const float*)d_in[5];
    const float* n1b = (const float*)d_in[6];
    const float* n2w = (const float*)d_in[7];
    const float* n2b = (const float*)d_in[8];
    const float* cr = (const float*)d_in[9];
    const float* cb = (const float*)d_in[10];
    const float* wih = (const float*)d_in[11];
    const float* whh = (const float*)d_in[12];
    const float* bih = (const float*)d_in[13];
    const float* bhh = (const float*)d_in[14];
    const float* l1w = (const float*)d_in[15];
    const float* l1b = (const float*)d_in[16];
    const float* l2w = (const float*)d_in[17];
    const float* l2b = (const float*)d_in[18];

    char* w = (char*)d_ws;
    size_t off = 0;
    float* F0 = (float*)(w + off); off += (size_t)NN * 64 * 4;
    float* F1 = (float*)(w + off); off += (size_t)NN * 64 * 4;
    float* hE = (float*)(w + off); off += (size_t)NE * 64 * 4;
    ushort* W2FH = (ushort*)(w + off); off += (size_t)64 * 4096 * 2;
    ushort* W2FL = (ushort*)(w + off); off += (size_t)64 * 4096 * 2;
    float* invd = (float*)(w + off); off += (size_t)NN * 4;
    int* deg = (int*)(w + off); off += (size_t)NN * 4;
    int* rowp = (int*)(w + off); off += (size_t)(NN + 1) * 4 + 252; off &= ~(size_t)255;
    int* fill = (int*)(w + off); off += (size_t)NN * 4;
    int* csrs = (int*)(w + off); off += (size_t)NE * 4;
    int* csre = (int*)(w + off); off += (size_t)NE * 4;

    hipMemsetAsync(deg, 0, NN * 4, stream);
    k_count<<<(NE + 255) / 256, 256, 0, stream>>>(ei, deg);
    k_scan<<<1, 1024, 0, stream>>>(deg, rowp, fill, invd);
    k_fill<<<(NE + 255) / 256, 256, 0, stream>>>(ei, fill, csrs, csre);
    k_w2f<<<1024, 256, 0, stream>>>(n2w, W2FH, W2FL);
    k_edge_h<<<NE / 4, 256, 0, stream>>>(ea, n1w, n1b, hE);
    k_lin0<<<NN / 4, 256, 0, stream>>>(x, l0w, l0b, F0);
    float* Fcur = F0;
    float* Fnxt = F1;
    for (int it = 0; it < 3; ++it) {
        k_mp<<<NN / 8, 1024, 0, stream>>>(Fcur, hE, rowp, csrs, csre, W2FH,
                                          W2FL, n2b, invd, cr, cb, wih, whh,
                                          bih, bhh, Fnxt);
        float* t = Fcur; Fcur = Fnxt; Fnxt = t;
    }
    k_final<<<NN / 4, 256, 0, stream>>>(Fcur, l1w, l1b, l2w, l2b, (float*)d_out);
}

// Round 6
// 669.995 us; speedup vs baseline: 1.3343x; 1.3343x over previous
//
#include <hip/hip_runtime.h>
#include <hip/hip_bf16.h>

#define NN 10000
#define NE 50000
#define FIN 40
#define FE 10
// L = 64

typedef float f32x4 __attribute__((ext_vector_type(4)));
typedef short s16x8 __attribute__((ext_vector_type(8)));

__device__ __forceinline__ float bcast(float v, int lane) {
    return __uint_as_float(__builtin_amdgcn_readlane(__float_as_uint(v), lane));
}
__device__ __forceinline__ ushort f2bf(float f) {
    uint u = __float_as_uint(f);
    uint r = (u + 0x7FFFu + ((u >> 16) & 1u)) >> 16;
    return (ushort)r;
}
__device__ __forceinline__ float bf2f(ushort h) {
    return __uint_as_float(((uint)h) << 16);
}

// ---------------- CSR build ----------------
__global__ void k_count(const int* __restrict__ ei, int* __restrict__ deg) {
    int e = blockIdx.x * 256 + threadIdx.x;
    if (e < NE) atomicAdd(&deg[ei[NE + e]], 1);
}

__global__ __launch_bounds__(1024) void k_scan(const int* __restrict__ deg,
                                               int* __restrict__ rowp,
                                               int* __restrict__ fill,
                                               float* __restrict__ invd) {
    __shared__ int wsum[16];
    __shared__ int chunkbase;
    int tid = threadIdx.x, lane = tid & 63, wv = tid >> 6;
    if (tid == 0) chunkbase = 0;
    __syncthreads();
    for (int base = 0; base < NN; base += 1024) {
        int idx = base + tid;
        int v = (idx < NN) ? deg[idx] : 0;
        int s = v;
#pragma unroll
        for (int off = 1; off < 64; off <<= 1) {
            int t = __shfl_up(s, off, 64);
            if (lane >= off) s += t;
        }
        if (lane == 63) wsum[wv] = s;
        __syncthreads();
        int carry = chunkbase;
        if (wv == 0 && lane < 16) {
            int x = wsum[lane];
#pragma unroll
            for (int off = 1; off < 16; off <<= 1) {
                int t = __shfl_up(x, off, 64);
                if (lane >= off) x += t;
            }
            wsum[lane] = x;  // inclusive over waves
        }
        __syncthreads();
        int wpre = (wv == 0) ? 0 : wsum[wv - 1];
        int incl = carry + wpre + s;
        if (idx < NN) {
            rowp[idx] = incl - v;
            fill[idx] = incl - v;
            invd[idx] = 1.0f / (float)(v > 0 ? v : 1);
        }
        __syncthreads();
        if (tid == 0) chunkbase = carry + wsum[15];
        __syncthreads();
    }
    if (tid == 0) rowp[NN] = NE;
}

__global__ void k_fill(const int* __restrict__ ei, int* __restrict__ fill,
                       int* __restrict__ csrs, int* __restrict__ csre) {
    int e = blockIdx.x * 256 + threadIdx.x;
    if (e < NE) {
        int d = ei[NE + e];
        int p = atomicAdd(&fill[d], 1);
        csrs[p] = ei[e];
        csre[p] = e;
    }
}

// ---------------- W2 split-bf16, transposed to [o][ki] (ki = k*64+i) ----------------
__global__ __launch_bounds__(256) void k_w2f(const float* __restrict__ n2w,
                                             ushort* __restrict__ W2FH,
                                             ushort* __restrict__ W2FL) {
    int lane = threadIdx.x & 63, wvl = threadIdx.x >> 6;
    int ki = blockIdx.x * 4 + wvl;
    float v = n2w[(size_t)ki * 64 + lane];
    ushort hi = f2bf(v);
    ushort lo = f2bf(v - bf2f(hi));
    W2FH[(size_t)lane * 4096 + ki] = hi;
    W2FL[(size_t)lane * 4096 + ki] = lo;
}

// ---------------- edge MLP: hE = relu(edge_attr @ nn1_w + nn1_b) ----------------
__global__ __launch_bounds__(256) void k_edge_h(const float* __restrict__ ea,
                                                const float* __restrict__ w1,
                                                const float* __restrict__ b1,
                                                float* __restrict__ hE) {
    int lane = threadIdx.x & 63, wv = threadIdx.x >> 6;
    int e = blockIdx.x * 4 + wv;
    float av = (lane < FE) ? ea[e * FE + lane] : 0.f;
    float acc = b1[lane];
#pragma unroll
    for (int j = 0; j < FE; ++j) acc += bcast(av, j) * w1[j * 64 + lane];
    hE[e * 64 + lane] = fmaxf(acc, 0.f);
}

// ---------------- lin0 ----------------
__global__ __launch_bounds__(256) void k_lin0(const float* __restrict__ x,
                                              const float* __restrict__ w0,
                                              const float* __restrict__ b0,
                                              float* __restrict__ F) {
    int lane = threadIdx.x & 63, wv = threadIdx.x >> 6;
    int n = blockIdx.x * 4 + wv;
    float xv = (lane < FIN) ? x[n * FIN + lane] : 0.f;
    float acc = b0[lane];
#pragma unroll
    for (int k = 0; k < FIN; ++k) acc += bcast(xv, k) * w0[k * 64 + lane];
    F[n * 64 + lane] = fmaxf(acc, 0.f);
}

// ---------------- fused NNConv + GRU via MFMA ----------------
// 16 waves = 16 nodes/block (625 blocks: best W2 amortization measured, R2).
// ANTI-SPILL: phase A is 4 passes over the edge list; pass c accumulates only
// G[16] (k-chunk c) in VGPR (lane=i), converts to bf16 into LDS, then all
// waves MFMA that chunk (otile=wv&3, kq=wv>>2). Per-thread live state ~40
// VGPR -> nothing to spill. G uses single bf16 (W2 keeps hi/lo split);
// error ~5e-4/iter vs 3.5e-3 threshold. hE read once total (disjoint 64B
// quarters per pass, uniform s_load). F gather x4 from L2-resident F.
__global__ __launch_bounds__(1024) void k_mp(
    const float* __restrict__ F, const float* __restrict__ hE,
    const int* __restrict__ rowp, const int* __restrict__ csrs,
    const int* __restrict__ csre,
    const ushort* __restrict__ W2FH, const ushort* __restrict__ W2FL,
    const float* __restrict__ B2, const float* __restrict__ invd,
    const float* __restrict__ Wroot, const float* __restrict__ broot,
    const float* __restrict__ Wih, const float* __restrict__ Whh,
    const float* __restrict__ bih, const float* __restrict__ bhh,
    float* __restrict__ Fout) {
    __shared__ __align__(16) char smem[37120];
    ushort(*GH)[1032] = (ushort(*)[1032])smem;            // [16][1032] 33024 B
    float(*Us)[64] = (float(*)[64])(smem + 33024);        // [16][64] 4096 B
    float(*Red)[256] = (float(*)[256])smem;               // union over GH, 16 KB
    float(*Agg)[64] = (float(*)[64])(smem + 16384);       // union over GH tail, 4 KB

    int tid = threadIdx.x, lane = tid & 63, wv = tid >> 6;
    int n = __builtin_amdgcn_readfirstlane(blockIdx.x * 16 + wv);
    int beg = __builtin_amdgcn_readfirstlane(rowp[n]);
    int end = __builtin_amdgcn_readfirstlane(rowp[n + 1]);

    f32x4 acc = {0.f, 0.f, 0.f, 0.f};
    int otile = wv & 3, kq = wv >> 2;
    int arow = lane & 15, agrp = lane >> 4;
    int o = otile * 16 + arow;
    const ushort* bhbase = W2FH + (size_t)o * 4096;
    const ushort* blbase = W2FL + (size_t)o * 4096;

#pragma unroll 1
    for (int c = 0; c < 4; ++c) {
        // ---- pass c of phase A: G[kk] = sum_e hE[e][c*16+kk] * F[src][lane]
        float G[16];
#pragma unroll
        for (int k = 0; k < 16; ++k) G[k] = 0.f;
        float usum = 0.f;
        for (int p = beg; p < end; ++p) {
            int s = __builtin_amdgcn_readfirstlane(csrs[p]);
            int e = __builtin_amdgcn_readfirstlane(csre[p]);
            float u = F[(size_t)s * 64 + lane];
            const float* hp = hE + (size_t)e * 64 + c * 16;  // uniform -> s_load
            if (c == 0) usum += u;
#pragma unroll
            for (int kk = 0; kk < 16; ++kk) G[kk] = fmaf(hp[kk], u, G[kk]);
        }
        if (c == 0) Us[wv][lane] = usum;
#pragma unroll
        for (int kk = 0; kk < 16; ++kk)
            GH[wv][kk * 64 + lane] = f2bf(G[kk]);
        __syncthreads();
        // ---- MFMA this chunk ----
#pragma unroll
        for (int s8 = 0; s8 < 8; ++s8) {
            int ki = (kq * 8 + s8) * 32 + agrp * 8;
            s16x8 ah = *(const s16x8*)&GH[arow][ki];
            s16x8 bh = *(const s16x8*)&bhbase[c * 1024 + ki];
            s16x8 bl = *(const s16x8*)&blbase[c * 1024 + ki];
            acc = __builtin_amdgcn_mfma_f32_16x16x32_bf16(ah, bh, acc, 0, 0, 0);
            acc = __builtin_amdgcn_mfma_f32_16x16x32_bf16(ah, bl, acc, 0, 0, 0);
        }
        __syncthreads();
    }

    // ---- reduce partial D over the 4 kq groups ----
    *(f32x4*)&Red[wv][lane * 4] = acc;
    __syncthreads();
    if (wv < 4) {
        int t = wv;
        f32x4 s0 = *(f32x4*)&Red[t][lane * 4];
        f32x4 s1 = *(f32x4*)&Red[t + 4][lane * 4];
        f32x4 s2 = *(f32x4*)&Red[t + 8][lane * 4];
        f32x4 s3 = *(f32x4*)&Red[t + 12][lane * 4];
        f32x4 ss = s0 + s1 + s2 + s3;
        // D[row=node=(lane>>4)*4+r][col=o=t*16+(lane&15)]
#pragma unroll
        for (int r = 0; r < 4; ++r)
            Agg[(lane >> 4) * 4 + r][t * 16 + (lane & 15)] = ss[r];
    }
    __syncthreads();

    // ---- epilogue per node-wave: mean + nn2_b + root -> relu -> m ----
    float b2t = 0.f;
#pragma unroll 8
    for (int i = 0; i < 64; ++i) b2t = fmaf(Us[wv][i], B2[i * 64 + lane], b2t);
    float a = (Agg[wv][lane] + b2t) * invd[n];
    const float* frow = F + (size_t)n * 64;  // uniform -> s_load
    float r = broot[lane];
#pragma unroll
    for (int k = 0; k < 64; ++k) r = fmaf(frow[k], Wroot[k * 64 + lane], r);
    float m = fmaxf(a + r, 0.f);

    // ---- fused single-step GRU: h' = (1-z)*ng + z*h ----
    float h = F[(size_t)n * 64 + lane];
    float sr = bih[lane] + bhh[lane];
    float sz = bih[64 + lane] + bhh[64 + lane];
    float gin = bih[128 + lane];
    float ghn = bhh[128 + lane];
#pragma unroll
    for (int k = 0; k < 64; ++k) {
        float mk = bcast(m, k), hk = bcast(h, k);
        const float* wi = &Wih[k * 192];
        const float* wh = &Whh[k * 192];
        sr = fmaf(mk, wi[lane], fmaf(hk, wh[lane], sr));
        sz = fmaf(mk, wi[64 + lane], fmaf(hk, wh[64 + lane], sz));
        gin = fmaf(mk, wi[128 + lane], gin);
        ghn = fmaf(hk, wh[128 + lane], ghn);
    }
    float rr = 1.f / (1.f + __expf(-sr));
    float zz = 1.f / (1.f + __expf(-sz));
    float ng = tanhf(gin + rr * ghn);
    Fout[(size_t)n * 64 + lane] = (1.f - zz) * ng + zz * h;
}

// ---------------- final ----------------
__global__ __launch_bounds__(256) void k_final(const float* __restrict__ F,
                                               const float* __restrict__ W1,
                                               const float* __restrict__ b1f,
                                               const float* __restrict__ W2l,
                                               const float* __restrict__ b2f,
                                               float* __restrict__ out) {
    int lane = threadIdx.x & 63, wv = threadIdx.x >> 6;
    int n = blockIdx.x * 4 + wv;
    float fv = F[n * 64 + lane];
    float acc = b1f[lane];
#pragma unroll
    for (int k = 0; k < 64; ++k) acc += bcast(fv, k) * W1[k * 64 + lane];
    acc = fmaxf(acc, 0.f);
    float p = acc * W2l[lane];
#pragma unroll
    for (int off = 32; off; off >>= 1) p += __shfl_xor(p, off, 64);
    if (lane == 0) out[n] = p + b2f[0];
}

extern "C" void kernel_launch(void* const* d_in, const int* in_sizes, int n_in,
                              void* d_out, int out_size, void* d_ws, size_t ws_size,
                              hipStream_t stream) {
    const float* x = (const float*)d_in[0];
    const int* ei = (const int*)d_in[1];
    const float* ea = (const float*)d_in[2];
    const float* l0w = (const float*)d_in[3];
    const float* l0b = (const float*)d_in[4];
    const float* n1w = (const float*)d_in[5];
    const float* n1b = (const float*)d_in[6];
    const float* n2w = (const float*)d_in[7];
    const float* n2b = (const float*)d_in[8];
    const float* cr = (const float*)d_in[9];
    const float* cb = (const float*)d_in[10];
    const float* wih = (const float*)d_in[11];
    const float* whh = (const float*)d_in[12];
    const float* bih = (const float*)d_in[13];
    const float* bhh = (const float*)d_in[14];
    const float* l1w = (const float*)d_in[15];
    const float* l1b = (const float*)d_in[16];
    const float* l2w = (const float*)d_in[17];
    const float* l2b = (const float*)d_in[18];

    char* w = (char*)d_ws;
    size_t off = 0;
    float* F0 = (float*)(w + off); off += (size_t)NN * 64 * 4;
    float* F1 = (float*)(w + off); off += (size_t)NN * 64 * 4;
    float* hE = (float*)(w + off); off += (size_t)NE * 64 * 4;
    ushort* W2FH = (ushort*)(w + off); off += (size_t)64 * 4096 * 2;
    ushort* W2FL = (ushort*)(w + off); off += (size_t)64 * 4096 * 2;
    float* invd = (float*)(w + off); off += (size_t)NN * 4;
    int* deg = (int*)(w + off); off += (size_t)NN * 4;
    int* rowp = (int*)(w + off); off += (size_t)(NN + 1) * 4 + 252; off &= ~(size_t)255;
    int* fill = (int*)(w + off); off += (size_t)NN * 4;
    int* csrs = (int*)(w + off); off += (size_t)NE * 4;
    int* csre = (int*)(w + off); off += (size_t)NE * 4;

    hipMemsetAsync(deg, 0, NN * 4, stream);
    k_count<<<(NE + 255) / 256, 256, 0, stream>>>(ei, deg);
    k_scan<<<1, 1024, 0, stream>>>(deg, rowp, fill, invd);
    k_fill<<<(NE + 255) / 256, 256, 0, stream>>>(ei, fill, csrs, csre);
    k_w2f<<<1024, 256, 0, stream>>>(n2w, W2FH, W2FL);
    k_edge_h<<<NE / 4, 256, 0, stream>>>(ea, n1w, n1b, hE);
    k_lin0<<<NN / 4, 256, 0, stream>>>(x, l0w, l0b, F0);
    float* Fcur = F0;
    float* Fnxt = F1;
    for (int it = 0; it < 3; ++it) {
        k_mp<<<NN / 16, 1024, 0, stream>>>(Fcur, hE, rowp, csrs, csre, W2FH,
                                           W2FL, n2b, invd, cr, cb, wih, whh,
                                           bih, bhh, Fnxt);
        float* t = Fcur; Fcur = Fnxt; Fnxt = t;
    }
    k_final<<<NN / 4, 256, 0, stream>>>(Fcur, l1w, l1b, l2w, l2b, (float*)d_out);
}